// Round 4
// baseline (22463.083 us; speedup 1.0000x reference)
//
#include <hip/hip_runtime.h>
#include <hip/hip_bf16.h>
#include <cstdint>
#include <cstddef>

// FFJORD: B=8192, D=128, H=1024, 2 bijectors x 32 RK4 steps x 4 stages.
// Round 4: FULL per-stage fusion. One kernel per RK4 stage: 256 blocks x 512
// threads, each block owns 32 rows. H1/H2 live entirely in LDS (XOR-swizzled);
// weights stream direct global->VGPR (L2-hot). Barrier-free GEMM K-loops.

#define BSZ 8192
#define DD  128
#define HH  1024

typedef __attribute__((ext_vector_type(8))) __bf16 bf16x8;
typedef __attribute__((ext_vector_type(4))) float  fx4;
typedef __attribute__((ext_vector_type(4))) unsigned short us4;

__device__ __forceinline__ unsigned short bf16bits(float x) {
  return __builtin_bit_cast(unsigned short, __float2bfloat16(x));
}

__device__ __forceinline__ float fast_tanh(float x) {
  float xc = fminf(fmaxf(x, -9.0f), 9.0f);
  float u = __expf(2.0f * xc);
  return (u - 1.0f) * __builtin_amdgcn_rcpf(u + 1.0f);
}

__device__ __forceinline__ void gll16(const void* g, void* l) {
  __builtin_amdgcn_global_load_lds((const __attribute__((address_space(1))) void*)g,
                                   (__attribute__((address_space(3))) void*)l, 16, 0, 0);
}

// ---------------- prep: copy x, bf16-cast x, transpose+cast weights ----------
__global__ void prep_kernel(const float* __restrict__ in0,
                            const float* __restrict__ W1,
                            const float* __restrict__ W2,
                            const float* __restrict__ W3,
                            float* __restrict__ xcur,
                            __hip_bfloat16* __restrict__ inbuf,
                            __hip_bfloat16* __restrict__ W1t,
                            __hip_bfloat16* __restrict__ W2t,
                            __hip_bfloat16* __restrict__ W3t) {
  size_t i = (size_t)blockIdx.x * blockDim.x + threadIdx.x;
  const size_t R0 = (size_t)BSZ * DD;
  const size_t R1 = 2u * 128 * 1024;
  const size_t R2 = 2u * 1024 * 1024;
  const size_t R3 = 2u * 1024 * 128;
  if (i < R0) {
    float v = in0[i];
    xcur[i] = v;
    inbuf[i] = __float2bfloat16(v);
    return;
  }
  i -= R0;
  if (i < R1) {  // W1t[bij][n][k] = W1[bij][k][n], k<128,n<1024
    size_t bij = i >> 17, rem = i & 131071;
    size_t n = rem >> 7, k = rem & 127;
    W1t[(bij << 17) + rem] = __float2bfloat16(W1[bij * (129 * 1024) + k * 1024 + n]);
    return;
  }
  i -= R1;
  if (i < R2) {  // W2t[bij][n][k] = W2[bij][k][n]
    size_t bij = i >> 20, rem = i & 1048575;
    size_t n = rem >> 10, k = rem & 1023;
    W2t[(bij << 20) + rem] = __float2bfloat16(W2[(bij << 20) + k * 1024 + n]);
    return;
  }
  i -= R2;
  if (i < R3) {  // W3t[bij][n][k] = W3[bij][k][n], n<128,k<1024
    size_t bij = i >> 17, rem = i & 131071;
    size_t n = rem >> 10, k = rem & 1023;
    W3t[(bij << 17) + rem] = __float2bfloat16(W3[(bij << 17) + k * 128 + n]);
  }
}

// ---------------- fused RK4-stage kernel -------------------------------------
// Per block: 32 rows. Phase A: H1 = tanh(X@W1 + b1 + t*tw) -> LDS.
// Phase B: H2 = tanh(H1@W2 + b2) -> LDS (reuse). Phase C: k = H2@W3 + b3,
// RK4 state update (xcur/kacc/nextin/out).
__global__ void __launch_bounds__(512, 2)
stage_kernel(const __hip_bfloat16* __restrict__ Xin,      // [8192][128] bf16
             const __hip_bfloat16* __restrict__ W1t,      // [1024][128]
             const __hip_bfloat16* __restrict__ W2t,      // [1024][1024]
             const __hip_bfloat16* __restrict__ W3t,      // [128][1024]
             const float* __restrict__ b1,
             const float* __restrict__ b2,
             const float* __restrict__ b3,
             const float* __restrict__ tw,
             float tval, float dt, int stage,
             const float* __restrict__ xcur,
             float* __restrict__ kacc,
             float* __restrict__ xout,
             __hip_bfloat16* __restrict__ nextin) {
  __shared__ __align__(16) char lds[82448];  // H 64KB | aux 16.9KB (X / k-bounce)
  char* Hs = lds;                    // [32 rows][2048 B] bf16, XOR-swizzled
  char* Xs = lds + 65536;            // [32 rows][256 B] bf16, XOR-swizzled
  float* kb = (float*)(lds + 65536); // [32][132] f32 (X dead by phase C)

  const int tid = threadIdx.x;
  const int lane = tid & 63;
  const int w = tid >> 6;            // 0..7
  const int l16 = lane & 15;
  const int lk8 = (lane >> 4) * 8;   // k-element offset of lane's frag chunk
  const int r0 = (lane >> 4) * 4;    // C-frag row base
  const int xa = (l16 & 7) << 4;     // XOR for A-frag rows (row&7 == l16&7)
  const int bid = blockIdx.x;
  const int m0 = ((bid & 7) * 32 + (bid >> 3)) * 32;  // XCD-contiguous rows
  const int nw0 = w * 128;           // wave's n-slice (phases A,B)

  // ---- stage X tile (32x128 bf16 = 8KB contiguous), pre-swizzled source ----
  {
    const char* Xg = (const char*)(Xin + (size_t)m0 * DD);
    int off = tid * 16;
    int soff = off ^ (((off >> 8) & 7) << 4);
    gll16(Xg + soff, Xs + off);
  }
  __syncthreads();

  fx4 acc[2][8];
#pragma unroll
  for (int i = 0; i < 2; ++i)
#pragma unroll
    for (int j = 0; j < 8; ++j) acc[i][j] = fx4{0.f, 0.f, 0.f, 0.f};

  // ---- phase A: H1 = tanh(X @ W1 + b1 + t*tw), K=128 ----
  {
    const char* Bg = (const char*)W1t;
    int bofs[8];
#pragma unroll
    for (int j = 0; j < 8; ++j) bofs[j] = (nw0 + j * 16 + l16) * 256 + lk8 * 2;
#pragma unroll
    for (int kk = 0; kk < 4; ++kk) {
      const int kb2 = kk * 64;  // k0*2 bytes
      bf16x8 a0 = *(const bf16x8*)(Xs + l16 * 256 + ((kb2 + lk8 * 2) ^ xa));
      bf16x8 a1 = *(const bf16x8*)(Xs + (16 + l16) * 256 + ((kb2 + lk8 * 2) ^ xa));
#pragma unroll
      for (int j = 0; j < 8; ++j) {
        bf16x8 bf = *(const bf16x8*)(Bg + bofs[j] + kb2);
        acc[0][j] = __builtin_amdgcn_mfma_f32_16x16x32_bf16(a0, bf, acc[0][j], 0, 0, 0);
        acc[1][j] = __builtin_amdgcn_mfma_f32_16x16x32_bf16(a1, bf, acc[1][j], 0, 0, 0);
      }
    }
#pragma unroll
    for (int j = 0; j < 8; ++j) {
      const int col = nw0 + j * 16 + l16;
      const float bb = b1[col] + tval * tw[col];
#pragma unroll
      for (int i = 0; i < 2; ++i)
#pragma unroll
        for (int r = 0; r < 4; ++r) {
          const int row = i * 16 + r0 + r;
          float v = fast_tanh(acc[i][j][r] + bb);
          *(unsigned short*)(Hs + row * 2048 + ((col * 2) ^ ((row & 7) << 4))) =
              bf16bits(v);
        }
    }
  }
  __syncthreads();  // H1 fully written

  // ---- phase B: H2 = tanh(H1 @ W2 + b2), K=1024, barrier-free K-loop ----
#pragma unroll
  for (int i = 0; i < 2; ++i)
#pragma unroll
    for (int j = 0; j < 8; ++j) acc[i][j] = fx4{0.f, 0.f, 0.f, 0.f};
  {
    const char* Bg = (const char*)W2t;
    int bofs[8];
#pragma unroll
    for (int j = 0; j < 8; ++j) bofs[j] = (nw0 + j * 16 + l16) * 2048 + lk8 * 2;
    bf16x8 bnext[8];
#pragma unroll
    for (int j = 0; j < 8; ++j) bnext[j] = *(const bf16x8*)(Bg + bofs[j]);
#pragma unroll 2
    for (int k0 = 0; k0 < 1024; k0 += 32) {
      bf16x8 bcur[8];
#pragma unroll
      for (int j = 0; j < 8; ++j) bcur[j] = bnext[j];
      const int kn = (k0 + 32 < 1024) ? (k0 + 32) * 2 : 0;  // wrap: dead on last
#pragma unroll
      for (int j = 0; j < 8; ++j) bnext[j] = *(const bf16x8*)(Bg + bofs[j] + kn);
      const int kb2 = k0 * 2;
      bf16x8 a0 = *(const bf16x8*)(Hs + l16 * 2048 + ((kb2 + lk8 * 2) ^ xa));
      bf16x8 a1 = *(const bf16x8*)(Hs + (16 + l16) * 2048 + ((kb2 + lk8 * 2) ^ xa));
#pragma unroll
      for (int j = 0; j < 8; ++j) {
        acc[0][j] = __builtin_amdgcn_mfma_f32_16x16x32_bf16(a0, bcur[j], acc[0][j], 0, 0, 0);
        acc[1][j] = __builtin_amdgcn_mfma_f32_16x16x32_bf16(a1, bcur[j], acc[1][j], 0, 0, 0);
      }
    }
  }
  __syncthreads();  // all waves done reading H1

  {  // epilogue B: H2 overwrites Hs
#pragma unroll
    for (int j = 0; j < 8; ++j) {
      const int col = nw0 + j * 16 + l16;
      const float bb = b2[col];
#pragma unroll
      for (int i = 0; i < 2; ++i)
#pragma unroll
        for (int r = 0; r < 4; ++r) {
          const int row = i * 16 + r0 + r;
          float v = fast_tanh(acc[i][j][r] + bb);
          *(unsigned short*)(Hs + row * 2048 + ((col * 2) ^ ((row & 7) << 4))) =
              bf16bits(v);
        }
    }
  }
  __syncthreads();  // H2 fully written

  // ---- phase C: k = H2 @ W3 + b3 (32x128, K=1024); 2 frags/wave ----
  {
    const int mf = w >> 2;          // 0..1
    const int nfb = (w & 3) * 2;    // 0,2,4,6
    fx4 c0 = fx4{0.f, 0.f, 0.f, 0.f}, c1 = fx4{0.f, 0.f, 0.f, 0.f};
    const char* Bg = (const char*)W3t;
    const int b0o = (nfb * 16 + l16) * 2048 + lk8 * 2;
    const int b1o = ((nfb + 1) * 16 + l16) * 2048 + lk8 * 2;
    const int arow = (mf * 16 + l16) * 2048;
#pragma unroll 4
    for (int k0 = 0; k0 < 1024; k0 += 32) {
      const int kb2 = k0 * 2;
      bf16x8 a = *(const bf16x8*)(Hs + arow + ((kb2 + lk8 * 2) ^ xa));
      bf16x8 bb0 = *(const bf16x8*)(Bg + b0o + kb2);
      bf16x8 bb1 = *(const bf16x8*)(Bg + b1o + kb2);
      c0 = __builtin_amdgcn_mfma_f32_16x16x32_bf16(a, bb0, c0, 0, 0, 0);
      c1 = __builtin_amdgcn_mfma_f32_16x16x32_bf16(a, bb1, c1, 0, 0, 0);
    }
#pragma unroll
    for (int r = 0; r < 4; ++r) {
      const int row = mf * 16 + r0 + r;
      kb[row * 132 + nfb * 16 + l16] = c0[r];
      kb[row * 132 + (nfb + 1) * 16 + l16] = c1[r];
    }
  }
  __syncthreads();

  // ---- RK4 state update, fully coalesced: 1024 float4 / 512 threads ----
#pragma unroll
  for (int q = 0; q < 2; ++q) {
    const int idx = tid + q * 512;
    const int row = idx >> 5, c4 = idx & 31;
    const int col0 = c4 * 4;
    const size_t gi = (size_t)(m0 + row) * DD + col0;
    const float4 b3v = *(const float4*)(b3 + col0);
    const float* kp = kb + row * 132 + col0;
    const float kv0 = kp[0] + b3v.x, kv1 = kp[1] + b3v.y;
    const float kv2 = kp[2] + b3v.z, kv3 = kp[3] + b3v.w;
    const float4 x = *(const float4*)(xcur + gi);
    float4 ka;
    float xs0, xs1, xs2, xs3;
    if (stage == 0) {
      ka = float4{kv0, kv1, kv2, kv3};
      *(float4*)(kacc + gi) = ka;
      xs0 = x.x + 0.5f * dt * kv0; xs1 = x.y + 0.5f * dt * kv1;
      xs2 = x.z + 0.5f * dt * kv2; xs3 = x.w + 0.5f * dt * kv3;
    } else if (stage == 1) {
      ka = *(const float4*)(kacc + gi);
      ka.x += 2.f * kv0; ka.y += 2.f * kv1; ka.z += 2.f * kv2; ka.w += 2.f * kv3;
      *(float4*)(kacc + gi) = ka;
      xs0 = x.x + 0.5f * dt * kv0; xs1 = x.y + 0.5f * dt * kv1;
      xs2 = x.z + 0.5f * dt * kv2; xs3 = x.w + 0.5f * dt * kv3;
    } else if (stage == 2) {
      ka = *(const float4*)(kacc + gi);
      ka.x += 2.f * kv0; ka.y += 2.f * kv1; ka.z += 2.f * kv2; ka.w += 2.f * kv3;
      *(float4*)(kacc + gi) = ka;
      xs0 = x.x + dt * kv0; xs1 = x.y + dt * kv1;
      xs2 = x.z + dt * kv2; xs3 = x.w + dt * kv3;
    } else {
      ka = *(const float4*)(kacc + gi);
      xs0 = x.x + (dt / 6.f) * (ka.x + kv0);
      xs1 = x.y + (dt / 6.f) * (ka.y + kv1);
      xs2 = x.z + (dt / 6.f) * (ka.z + kv2);
      xs3 = x.w + (dt / 6.f) * (ka.w + kv3);
      *(float4*)(xout + gi) = float4{xs0, xs1, xs2, xs3};
    }
    us4 nv;
    nv.x = bf16bits(xs0); nv.y = bf16bits(xs1);
    nv.z = bf16bits(xs2); nv.w = bf16bits(xs3);
    *(us4*)(nextin + gi) = nv;
  }
}

// ---------------- host -------------------------------------------------------
extern "C" void kernel_launch(void* const* d_in, const int* in_sizes, int n_in,
                              void* d_out, int out_size, void* d_ws, size_t ws_size,
                              hipStream_t stream) {
  const float* inputs = (const float*)d_in[0];
  const float* W1 = (const float*)d_in[1];
  const float* b1 = (const float*)d_in[2];
  const float* W2 = (const float*)d_in[3];
  const float* b2 = (const float*)d_in[4];
  const float* W3 = (const float*)d_in[5];
  const float* b3 = (const float*)d_in[6];
  float* out = (float*)d_out;

  char* ws = (char*)d_ws;
  float* xcur = (float*)ws;                                      // 4 MB
  float* kacc = (float*)(ws + (4u << 20));                       // 4 MB
  __hip_bfloat16* inbuf = (__hip_bfloat16*)(ws + (8u << 20));    // 2 MB
  __hip_bfloat16* W1t = (__hip_bfloat16*)(ws + (10u << 20));     // 512 KB
  __hip_bfloat16* W2t = (__hip_bfloat16*)(ws + (10u << 20) + (512u << 10)); // 4 MB
  __hip_bfloat16* W3t = (__hip_bfloat16*)(ws + (14u << 20) + (512u << 10)); // 512 KB

  {
    const size_t total = (size_t)BSZ * DD + 2u * 128 * 1024 + 2u * 1024 * 1024 + 2u * 1024 * 128;
    const int blocks = (int)((total + 255) / 256);
    prep_kernel<<<blocks, 256, 0, stream>>>(inputs, W1, W2, W3, xcur, inbuf, W1t, W2t, W3t);
  }

  const float dt = 1.0f / 32.0f;
  for (int bij = 0; bij < 2; ++bij) {
    const __hip_bfloat16* w1t_b = W1t + (size_t)bij * 128 * 1024;
    const __hip_bfloat16* w2t_b = W2t + (size_t)bij * 1024 * 1024;
    const __hip_bfloat16* w3t_b = W3t + (size_t)bij * 1024 * 128;
    const float* b1_b = b1 + (size_t)bij * 1024;
    const float* b2_b = b2 + (size_t)bij * 1024;
    const float* b3_b = b3 + (size_t)bij * 128;
    const float* tw = W1 + (size_t)bij * (129 * 1024) + 128 * 1024;  // time row

    for (int step = 0; step < 32; ++step) {
      for (int s = 0; s < 4; ++s) {
        const float t = step * dt + (s == 0 ? 0.f : (s == 3 ? dt : 0.5f * dt));
        const bool last = (bij == 1 && step == 31 && s == 3);
        stage_kernel<<<256, 512, 0, stream>>>(
            inbuf, w1t_b, w2t_b, w3t_b, b1_b, b2_b, b3_b, tw,
            t, dt, s, xcur, kacc, last ? out : xcur, inbuf);
      }
    }
  }
}